// Round 12
// baseline (1892.252 us; speedup 1.0000x reference)
//
#include <hip/hip_runtime.h>
#include <hip/hip_fp16.h>

#define NN 100000
#define EC 6400000
#define ED 400000
#define BN_EPS 1e-5f
#define NSB ((NN + 255) >> 8)    // 391 buckets of 256 dst nodes
#define NCH 256                  // edge chunks == scatter/hist grid
#define CSR_CAP 19200            // LDS edge-buffer capacity (bucket max ~17K)
#define TILE 4096                // src subtile rows
#define NSUB ((NN + TILE - 1) / TILE)   // 25
#define CHUNK_OF(E) (((((E) + NCH - 1) / NCH) + 3) & ~3)   // 4-aligned chunk

// ---------------- preprocessing ----------------

__global__ __launch_bounds__(1024)
void hist_pass(const int* __restrict__ ei, int E, int* __restrict__ bhist) {
    __shared__ int h[NSB];
    for (int i = threadIdx.x; i < NSB; i += 1024) h[i] = 0;
    __syncthreads();
    int k = blockIdx.x;
    int chunk = CHUNK_OF(E);
    int beg = k * chunk, end = min(E, beg + chunk);
    for (int e = beg + threadIdx.x * 4; e < end; e += 1024 * 4) {
        int4 d4 = *(const int4*)&ei[E + e];
        atomicAdd(&h[d4.x >> 8], 1);
        atomicAdd(&h[d4.y >> 8], 1);
        atomicAdd(&h[d4.z >> 8], 1);
        atomicAdd(&h[d4.w >> 8], 1);
    }
    __syncthreads();
    for (int i = threadIdx.x; i < NSB; i += 1024) bhist[i * NCH + k] = h[i];
}

__global__ __launch_bounds__(256)
void row_scan(int* __restrict__ bhist, int* __restrict__ total) {
    int b = blockIdx.x;
    int* row = bhist + b * NCH;
    __shared__ int wsum[4];
    int lane = threadIdx.x & 63, w = threadIdx.x >> 6;
    int v = row[threadIdx.x];
    int x = v;
    #pragma unroll
    for (int sh = 1; sh < 64; sh <<= 1) { int y = __shfl_up(x, sh); if (lane >= sh) x += y; }
    if (lane == 63) wsum[w] = x;
    __syncthreads();
    int wb = 0;
    #pragma unroll
    for (int j = 0; j < 4; ++j) if (j < w) wb += wsum[j];
    row[threadIdx.x] = wb + x - v;
    if (threadIdx.x == 255) total[b] = wb + x;
}

__global__ void bucket_base(const int* __restrict__ total, int* __restrict__ bbase) {
    __shared__ int wsum[4];
    __shared__ int carry;
    if (threadIdx.x == 0) carry = 0;
    __syncthreads();
    int lane = threadIdx.x & 63, w = threadIdx.x >> 6;
    for (int s = 0; s < NSB; s += 256) {
        int idx = s + threadIdx.x;
        int v = (idx < NSB) ? total[idx] : 0;
        int x = v;
        #pragma unroll
        for (int sh = 1; sh < 64; sh <<= 1) { int y = __shfl_up(x, sh); if (lane >= sh) x += y; }
        if (lane == 63) wsum[w] = x;
        __syncthreads();
        int wb = 0;
        #pragma unroll
        for (int j = 0; j < 4; ++j) if (j < w) wb += wsum[j];
        int all = wsum[0] + wsum[1] + wsum[2] + wsum[3];
        if (idx < NSB) bbase[idx] = carry + wb + x - v;
        __syncthreads();
        if (threadIdx.x == 0) carry += all;
        __syncthreads();
    }
}

__global__ __launch_bounds__(1024)
void scatter_pairs(const int* __restrict__ ei, int E,
                   const int* __restrict__ bhist, const int* __restrict__ bbase,
                   unsigned* __restrict__ packed) {
    __shared__ int cur[NSB];
    int k = blockIdx.x;
    for (int b = threadIdx.x; b < NSB; b += 1024)
        cur[b] = bbase[b] + bhist[b * NCH + k];
    __syncthreads();
    int chunk = CHUNK_OF(E);
    int beg = k * chunk, end = min(E, beg + chunk);
    for (int e = beg + threadIdx.x * 4; e < end; e += 1024 * 4) {
        int4 s4 = *(const int4*)&ei[e];
        int4 d4 = *(const int4*)&ei[E + e];
        { int p = atomicAdd(&cur[d4.x >> 8], 1); packed[p] = (unsigned)s4.x | ((unsigned)(d4.x & 255) << 17); }
        { int p = atomicAdd(&cur[d4.y >> 8], 1); packed[p] = (unsigned)s4.y | ((unsigned)(d4.y & 255) << 17); }
        { int p = atomicAdd(&cur[d4.z >> 8], 1); packed[p] = (unsigned)s4.z | ((unsigned)(d4.z & 255) << 17); }
        { int p = atomicAdd(&cur[d4.w >> 8], 1); packed[p] = (unsigned)s4.w | ((unsigned)(d4.w & 255) << 17); }
    }
}

// eic: group each bucket's edges by src subtile (NSUB bins); payload
// (ldst<<12)|(src&4095). Also emits deg/inv and per-bin offsets gbin.
__global__ __launch_bounds__(256)
void sb_group(const unsigned* __restrict__ packed,
              const int* __restrict__ bbase, const int* __restrict__ total,
              unsigned* __restrict__ packed2, int* __restrict__ gbin,
              int* __restrict__ deg, float* __restrict__ inv) {
    __shared__ int hn[256];
    __shared__ int hb[NSUB];
    __shared__ int boff[NSUB + 1];
    __shared__ int cur[NSUB];
    __shared__ unsigned ebuf[CSR_CAP];
    int b = blockIdx.x;
    int ebeg = bbase[b], ecnt = total[b];
    int node0 = b << 8;
    int nn = min(256, NN - node0);
    hn[threadIdx.x] = 0;
    if (threadIdx.x < NSUB) hb[threadIdx.x] = 0;
    __syncthreads();
    for (int e = threadIdx.x; e < ecnt; e += 256) {
        unsigned u = packed[ebeg + e];
        atomicAdd(&hn[u >> 17], 1);
        atomicAdd(&hb[(u & 0x1FFFFu) >> 12], 1);
    }
    __syncthreads();
    if (threadIdx.x == 0) {
        int s = 0;
        for (int i = 0; i < NSUB; ++i) { boff[i] = s; s += hb[i]; }
        boff[NSUB] = s;
    }
    __syncthreads();
    if (threadIdx.x <= NSUB) gbin[b * (NSUB + 1) + threadIdx.x] = ebeg + boff[threadIdx.x];
    if (threadIdx.x < NSUB) cur[threadIdx.x] = boff[threadIdx.x];
    if (threadIdx.x < nn) {
        int node = node0 + threadIdx.x;
        int d = hn[threadIdx.x];
        deg[node] = d;
        inv[node] = 1.0f / (float)(d > 1 ? d : 1);
    }
    __syncthreads();
    if (ecnt <= CSR_CAP) {
        for (int e = threadIdx.x; e < ecnt; e += 256) {
            unsigned u = packed[ebeg + e];
            int bin = (int)((u & 0x1FFFFu) >> 12);
            int p = atomicAdd(&cur[bin], 1);
            ebuf[p] = ((u >> 17) << 12) | (u & 0xFFFu);
        }
        __syncthreads();
        for (int e = threadIdx.x; e < ecnt; e += 256) packed2[ebeg + e] = ebuf[e];
    } else {   // fallback (never fires for this data)
        for (int e = threadIdx.x; e < ecnt; e += 256) {
            unsigned u = packed[ebeg + e];
            int bin = (int)((u & 0x1FFFFu) >> 12);
            int p = atomicAdd(&cur[bin], 1);
            packed2[ebeg + p] = ((u >> 17) << 12) | (u & 0xFFFu);
        }
    }
}

// eid: exact per-node CSR (R11 version, used by the small gather layer)
__global__ __launch_bounds__(256)
void sb_csr(const unsigned* __restrict__ packed,
            const int* __restrict__ bbase, const int* __restrict__ total,
            int* __restrict__ csr, int* __restrict__ offs, int* __restrict__ deg,
            float* __restrict__ inv) {
    __shared__ int h[256];
    __shared__ int loff[256];
    __shared__ int ws2[4];
    __shared__ int ebuf[CSR_CAP];
    int b = blockIdx.x;
    int ebeg = bbase[b], ecnt = total[b];
    int node0 = b << 8;
    int nn = min(256, NN - node0);
    h[threadIdx.x] = 0;
    __syncthreads();
    for (int e = threadIdx.x; e < ecnt; e += 256)
        atomicAdd(&h[packed[ebeg + e] >> 17], 1);
    __syncthreads();
    {
        int lane = threadIdx.x & 63, w = threadIdx.x >> 6;
        int v = h[threadIdx.x], x = v;
        #pragma unroll
        for (int sh = 1; sh < 64; sh <<= 1) { int y = __shfl_up(x, sh); if (lane >= sh) x += y; }
        if (lane == 63) ws2[w] = x;
        __syncthreads();
        int wb = 0;
        #pragma unroll
        for (int j = 0; j < 4; ++j) if (j < w) wb += ws2[j];
        int excl = wb + x - v;
        loff[threadIdx.x] = excl;
        if (threadIdx.x < nn) {
            int node = node0 + threadIdx.x;
            offs[node] = ebeg + excl;
            deg[node]  = v;
            inv[node]  = 1.0f / (float)(v > 1 ? v : 1);
        }
    }
    __syncthreads();
    if (ecnt <= CSR_CAP) {
        for (int e = threadIdx.x; e < ecnt; e += 256) {
            unsigned u = packed[ebeg + e];
            int p = atomicAdd(&loff[u >> 17], 1);
            ebuf[p] = (int)(u & 0x1FFFF);
        }
        __syncthreads();
        for (int e = threadIdx.x; e < ecnt; e += 256) csr[ebeg + e] = (int)ebuf[e];
    } else {
        for (int e = threadIdx.x; e < ecnt; e += 256) {
            unsigned u = packed[ebeg + e];
            int p = atomicAdd(&loff[u >> 17], 1);
            csr[ebeg + p] = (int)(u & 0x1FFFF);
        }
    }
}

// prep: x (f32 [NN,5]) -> f32 padded [NN,8] + fp16 copy; W1 -> padded 8x8
__global__ __launch_bounds__(256)
void prep_misc(const float* __restrict__ x, const float* __restrict__ W1l,
               const float* __restrict__ W1r, float* __restrict__ xp,
               __half* __restrict__ xp16,
               float* __restrict__ W1lp, float* __restrict__ W1rp) {
    int t = blockIdx.x * 256 + threadIdx.x;
    if (t < 64) {
        int f = t >> 3, k = t & 7;
        W1lp[t] = (k < 5) ? W1l[f * 5 + k] : 0.f;
        W1rp[t] = (k < 5) ? W1r[f * 5 + k] : 0.f;
    }
    for (int idx = t; idx < NN * 8; idx += gridDim.x * 256) {
        int f = idx & 7, i = idx >> 3;
        float v = (f < 5) ? x[i * 5 + f] : 0.f;
        xp[idx] = v;
        xp16[idx] = __float2half(v);
    }
}

// ---------------- eic layer v7: staged-SpMM ----------------
// Random-line gather wall (~8 cyc/edge across R5/R8/R9/R10/R11) is bypassed:
// stream src subtiles (fp16, 64KB) into LDS coalesced, then edges read rows
// from LDS and accumulate into LDS f32 acc[256][9] (stride 9: dst*9+k mod 32
// spreads all banks). Block = dst bucket; edges pre-grouped by src subtile.
template<bool APPLY_BN>
__global__ __launch_bounds__(256)
void sage_spmm(const float* __restrict__ hin,       // f32 rows (self-term)
               const __half* __restrict__ hin16,    // fp16 rows (staged)
               const float* __restrict__ stats_in,  // [k*16]=sum, [(8+k)*16]=sumsq
               const float* __restrict__ gin, const float* __restrict__ bin,
               const int* __restrict__ deg, const float* __restrict__ inv,
               const int* __restrict__ gbin, const unsigned* __restrict__ packed2,
               const float* __restrict__ Wl, const float* __restrict__ Wr,
               float* __restrict__ hout, __half* __restrict__ hout16,
               float* __restrict__ stats_out) {
    __shared__ __align__(16) unsigned short tile[TILE * 8];   // 64 KB
    __shared__ float acc[256 * 9];                            // 9.2 KB
    __shared__ float bl[16];
    int tid = threadIdx.x;
    int b = blockIdx.x;
    int node0 = b << 8;
    for (int i = tid; i < 256 * 9; i += 256) acc[i] = 0.f;
    if (tid < 16) bl[tid] = 0.f;

    float sc[8], sh[8];
    #pragma unroll
    for (int k = 0; k < 8; ++k) { sc[k] = 1.f; sh[k] = 0.f; }
    if constexpr (APPLY_BN) {
        #pragma unroll
        for (int k = 0; k < 8; ++k) {
            float m = stats_in[k * 16] * (1.f / NN);
            float v = stats_in[(8 + k) * 16] * (1.f / NN) - m * m;
            float is = rsqrtf(v + BN_EPS);
            sc[k] = gin[k] * is;
            sh[k] = bin[k] - m * sc[k];
        }
    }

    const int* gb = gbin + b * (NSUB + 1);
    for (int sub = 0; sub < NSUB; ++sub) {
        int rs = sub * TILE;
        int rows = min(TILE, NN - rs);
        __syncthreads();
        const uint4* gsrc = (const uint4*)(hin16 + (size_t)rs * 8);
        uint4* lt = (uint4*)tile;
        for (int r = tid; r < rows; r += 256) lt[r] = gsrc[r];   // coalesced stream
        __syncthreads();
        int e1 = gb[sub + 1];
        for (int e = gb[sub] + tid; e < e1; e += 256) {
            unsigned u = packed2[e];
            int ld = (int)(u >> 12);
            int sl = (int)(u & 0xFFFu);
            uint4 rv = lt[sl];                                   // LDS 16B row read
            float2 p0 = __half22float2(*(const __half2*)&rv.x);
            float2 p1 = __half22float2(*(const __half2*)&rv.y);
            float2 p2 = __half22float2(*(const __half2*)&rv.z);
            float2 p3 = __half22float2(*(const __half2*)&rv.w);
            float* a = &acc[ld * 9];
            atomicAdd(a + 0, p0.x); atomicAdd(a + 1, p0.y);
            atomicAdd(a + 2, p1.x); atomicAdd(a + 3, p1.y);
            atomicAdd(a + 4, p2.x); atomicAdd(a + 5, p2.y);
            atomicAdd(a + 6, p3.x); atomicAdd(a + 7, p3.y);
        }
    }
    __syncthreads();

    // finish: thread t = node node0+t, fully in-thread
    int nn = min(256, NN - node0);
    bool ok = tid < nn;
    int ii = node0 + (ok ? tid : (nn - 1));
    int d = deg[ii];
    float im = inv[ii];
    float dnz = (d > 0) ? 1.f : 0.f;
    const float4* hp = (const float4*)(hin + (size_t)ii * 8);
    float4 h0 = hp[0], h1 = hp[1];
    float hk[8] = { h0.x, h0.y, h0.z, h0.w, h1.x, h1.y, h1.z, h1.w };
    float mk[8], hh[8];
    #pragma unroll
    for (int k = 0; k < 8; ++k) {
        mk[k] = fmaf(sc[k], acc[tid * 9 + k] * im, sh[k] * dnz);
        hh[k] = fmaf(sc[k], hk[k], sh[k]);
    }
    float y[8];
    float n2 = 0.f;
    #pragma unroll
    for (int f = 0; f < 8; ++f) {
        float t = 0.f;
        #pragma unroll
        for (int k = 0; k < 8; ++k) {
            t = fmaf(mk[k], Wl[f * 8 + k], t);    // uniform index -> scalar loads
            t = fmaf(hh[k], Wr[f * 8 + k], t);
        }
        y[f] = t;
        n2 += t * t;
    }
    float is = 1.f / fmaxf(sqrtf(n2), 1e-12f);
    float rv[8];
    #pragma unroll
    for (int f = 0; f < 8; ++f) rv[f] = ok ? fmaxf(y[f] * is, 0.f) : 0.f;
    if (ok) {
        float4 o0 = { rv[0], rv[1], rv[2], rv[3] };
        float4 o1 = { rv[4], rv[5], rv[6], rv[7] };
        float4* op = (float4*)(hout + (size_t)ii * 8);
        op[0] = o0; op[1] = o1;
        __half2 q0 = __floats2half2_rn(rv[0], rv[1]);
        __half2 q1 = __floats2half2_rn(rv[2], rv[3]);
        __half2 q2 = __floats2half2_rn(rv[4], rv[5]);
        __half2 q3 = __floats2half2_rn(rv[6], rv[7]);
        uint4 hq;
        hq.x = *(unsigned*)&q0; hq.y = *(unsigned*)&q1;
        hq.z = *(unsigned*)&q2; hq.w = *(unsigned*)&q3;
        *(uint4*)(hout16 + (size_t)ii * 8) = hq;
    }
    // stats: wave shuffle-reduce then one atomic per wave per feature
    #pragma unroll
    for (int f = 0; f < 8; ++f) {
        float s1 = rv[f], s2 = rv[f] * rv[f];
        #pragma unroll
        for (int m = 1; m < 64; m <<= 1) { s1 += __shfl_xor(s1, m); s2 += __shfl_xor(s2, m); }
        if ((tid & 63) == 0) { atomicAdd(&bl[f], s1); atomicAdd(&bl[8 + f], s2); }
    }
    __syncthreads();
    if (tid < 16) atomicAdd(&stats_out[tid * 16], bl[tid]);   // 1 cache line per feature
}

// ---------------- eid layer: R11 gather kernel (400K edges, proven) ----------
template<bool APPLY_BN>
__global__ __launch_bounds__(256)
void sage_layer8(const float* __restrict__ hin,
                 const __half* __restrict__ hin16,
                 const float* __restrict__ stats_in,
                 const float* __restrict__ gin, const float* __restrict__ bin,
                 const int* __restrict__ offs, const int* __restrict__ deg,
                 const int* __restrict__ csr, const float* __restrict__ inv,
                 const float* __restrict__ Wl, const float* __restrict__ Wr,
                 float* __restrict__ hout, __half* __restrict__ hout16,
                 float* __restrict__ stats_out) {
    __shared__ float bl[16];
    int tid = threadIdx.x;
    if (tid < 16) bl[tid] = 0.f;
    __syncthreads();
    int wave = tid >> 6, lane = tid & 63, g = lane >> 3, f = lane & 7;

    float sc[8], sh[8];
    #pragma unroll
    for (int k = 0; k < 8; ++k) { sc[k] = 1.f; sh[k] = 0.f; }
    if constexpr (APPLY_BN) {
        #pragma unroll
        for (int k = 0; k < 8; ++k) {
            float m = stats_in[k * 16] * (1.f / NN);
            float v = stats_in[(8 + k) * 16] * (1.f / NN) - m * m;
            float is = rsqrtf(v + BN_EPS);
            sc[k] = gin[k] * is;
            sh[k] = bin[k] - m * sc[k];
        }
    }
    float wl[8], wr[8];
    #pragma unroll
    for (int k = 0; k < 8; ++k) { wl[k] = Wl[f * 8 + k]; wr[k] = Wr[f * 8 + k]; }

    float acc_r = 0.f, acc_r2 = 0.f;
    const int stride = gridDim.x * 32;
    for (int i0 = (blockIdx.x * 4 + wave) * 8; i0 < NN; i0 += stride) {
        int i = i0 + g;
        int ic = min(i, NN - 1);
        bool ok = (i < NN);
        int d = ok ? deg[ic] : 0;
        int o = offs[ic];
        float a0 = 0, a1 = 0, a2 = 0, a3 = 0, a4 = 0, a5 = 0, a6 = 0, a7 = 0;
        for (int b = 0; b < d; b += 8) {
            int e = b + f;
            int cv = csr[o + e];
            float m = (e < d) ? 1.f : 0.f;
            unsigned s = min((unsigned)cv & 0x1FFFFu, (unsigned)(NN - 1));
            uint4 rv = *(const uint4*)(hin16 + (size_t)s * 8);
            float2 p0 = __half22float2(*(const __half2*)&rv.x);
            float2 p1 = __half22float2(*(const __half2*)&rv.y);
            float2 p2 = __half22float2(*(const __half2*)&rv.z);
            float2 p3 = __half22float2(*(const __half2*)&rv.w);
            a0 = fmaf(p0.x, m, a0); a1 = fmaf(p0.y, m, a1);
            a2 = fmaf(p1.x, m, a2); a3 = fmaf(p1.y, m, a3);
            a4 = fmaf(p2.x, m, a4); a5 = fmaf(p2.y, m, a5);
            a6 = fmaf(p3.x, m, a6); a7 = fmaf(p3.y, m, a7);
        }
        #pragma unroll
        for (int msk = 1; msk < 8; msk <<= 1) {
            a0 += __shfl_xor(a0, msk); a1 += __shfl_xor(a1, msk);
            a2 += __shfl_xor(a2, msk); a3 += __shfl_xor(a3, msk);
            a4 += __shfl_xor(a4, msk); a5 += __shfl_xor(a5, msk);
            a6 += __shfl_xor(a6, msk); a7 += __shfl_xor(a7, msk);
        }
        float im = inv[ic];
        float dnz = (d > 0) ? 1.f : 0.f;
        const float4* hp = (const float4*)(hin + (size_t)ic * 8);
        float4 h0 = hp[0];
        float4 h1 = hp[1];
        float hk[8] = { h0.x, h0.y, h0.z, h0.w, h1.x, h1.y, h1.z, h1.w };
        float ac[8] = { a0, a1, a2, a3, a4, a5, a6, a7 };
        float y = 0.f;
        #pragma unroll
        for (int k = 0; k < 8; ++k) {
            float mk = fmaf(sc[k], ac[k] * im, sh[k] * dnz);
            float hh = fmaf(sc[k], hk[k], sh[k]);
            y = fmaf(mk, wl[k], y);
            y = fmaf(hh, wr[k], y);
        }
        float n2 = y * y;
        n2 += __shfl_xor(n2, 1);
        n2 += __shfl_xor(n2, 2);
        n2 += __shfl_xor(n2, 4);
        float z = y / fmaxf(sqrtf(n2), 1e-12f);
        float r = fmaxf(z, 0.f);
        r = ok ? r : 0.f;
        if (ok) {
            hout[(size_t)i * 8 + f] = r;
            hout16[(size_t)i * 8 + f] = __float2half(r);
        }
        acc_r += r;
        acc_r2 += r * r;
    }
    atomicAdd(&bl[f], acc_r);
    atomicAdd(&bl[8 + f], acc_r2);
    __syncthreads();
    if (tid < 16) atomicAdd(&stats_out[tid * 16], bl[tid]);
}

__global__ void apply_bn_out(const float* __restrict__ hin,
                             const float* __restrict__ stats,
                             const float* __restrict__ g, const float* __restrict__ b,
                             float* __restrict__ out) {
    int t = blockIdx.x * blockDim.x + threadIdx.x;
    if (t >= NN * 8) return;
    int f = t & 7;
    float m = stats[f * 16] * (1.0f / NN);
    float v = stats[(8 + f) * 16] * (1.0f / NN) - m * m;
    float sc = g[f] * rsqrtf(v + BN_EPS);
    float sh = b[f] - m * sc;
    out[t] = fmaf(hin[t], sc, sh);
}

// ---------------- launch ----------------

static inline char* bump(char*& p, size_t bytes) {
    char* r = p;
    p += (bytes + 255) & ~(size_t)255;
    return r;
}

extern "C" void kernel_launch(void* const* d_in, const int* in_sizes, int n_in,
                              void* d_out, int out_size, void* d_ws, size_t ws_size,
                              hipStream_t stream) {
    const float* x   = (const float*)d_in[0];
    const int* eic   = (const int*)d_in[1];
    const int* eid   = (const int*)d_in[2];
    const float* W1l = (const float*)d_in[3];
    const float* W1r = (const float*)d_in[4];
    const float* W2l = (const float*)d_in[5];
    const float* W2r = (const float*)d_in[6];
    const float* W3l = (const float*)d_in[7];
    const float* W3r = (const float*)d_in[8];
    const float* W4l = (const float*)d_in[9];
    const float* W4r = (const float*)d_in[10];
    const float* g1 = (const float*)d_in[11];
    const float* b1 = (const float*)d_in[12];
    const float* g2 = (const float*)d_in[13];
    const float* b2 = (const float*)d_in[14];
    const float* g3 = (const float*)d_in[15];
    const float* b3 = (const float*)d_in[16];
    const float* g4 = (const float*)d_in[17];
    const float* b4 = (const float*)d_in[18];
    float* out = (float*)d_out;

    char* p = (char*)d_ws;
    float* stats   = (float*)bump(p, 5 * 256 * 4);   // zero region (only this)
    size_t zero_bytes = (size_t)(p - (char*)d_ws);
    int*   bhist_c = (int*)  bump(p, (size_t)NSB * NCH * 4);
    int*   bhist_d = (int*)  bump(p, (size_t)NSB * NCH * 4);
    int*   total_c = (int*)  bump(p, NSB * 4);
    int*   bbase_c = (int*)  bump(p, NSB * 4);
    int*   total_d = (int*)  bump(p, NSB * 4);
    int*   bbase_d = (int*)  bump(p, NSB * 4);
    int*   gbin_c  = (int*)  bump(p, (size_t)NSB * (NSUB + 1) * 4);
    int*   deg_c   = (int*)  bump(p, NN * 4);
    float* inv_c   = (float*)bump(p, NN * 4);
    int*   offs_d  = (int*)  bump(p, NN * 4);
    int*   deg_d   = (int*)  bump(p, NN * 4);
    float* inv_d   = (float*)bump(p, NN * 4);
    unsigned* packed2_c = (unsigned*)bump(p, (size_t)EC * 4);   // persistent (eic layers)
    int*   csr_d   = (int*)  bump(p, ((size_t)ED + 64) * 4);    // +64 over-read pad
    float* xp32    = (float*)bump(p, (size_t)NN * 8 * 4);
    __half* xp16   = (__half*)bump(p, (size_t)NN * 8 * 2);
    float* W1lp    = (float*)bump(p, 64 * 4);
    float* W1rp    = (float*)bump(p, 64 * 4);
    unsigned* packed_d = (unsigned*)bump(p, (size_t)ED * 4);
    // packed_c dead after sb_group; overlay activation ping-pong (f32 + fp16)
    char* pc = p;
    unsigned* packed_c = (unsigned*)bump(p, (size_t)EC * 4);
    char* pr = pc;
    float*  r_a   = (float*) bump(pr, (size_t)NN * 8 * 4);
    float*  r_b   = (float*) bump(pr, (size_t)NN * 8 * 4);
    __half* h16_a = (__half*)bump(pr, (size_t)NN * 8 * 2);
    __half* h16_b = (__half*)bump(pr, (size_t)NN * 8 * 2);
    (void)ws_size; (void)in_sizes; (void)n_in; (void)out_size;

    hipMemsetAsync(d_ws, 0, zero_bytes, stream);

    hist_pass<<<NCH, 1024, 0, stream>>>(eic, EC, bhist_c);
    hist_pass<<<NCH, 1024, 0, stream>>>(eid, ED, bhist_d);
    row_scan<<<NSB, 256, 0, stream>>>(bhist_c, total_c);
    row_scan<<<NSB, 256, 0, stream>>>(bhist_d, total_d);
    bucket_base<<<1, 256, 0, stream>>>(total_c, bbase_c);
    bucket_base<<<1, 256, 0, stream>>>(total_d, bbase_d);
    scatter_pairs<<<NCH, 1024, 0, stream>>>(eic, EC, bhist_c, bbase_c, packed_c);
    scatter_pairs<<<NCH, 1024, 0, stream>>>(eid, ED, bhist_d, bbase_d, packed_d);
    sb_group<<<NSB, 256, 0, stream>>>(packed_c, bbase_c, total_c, packed2_c, gbin_c, deg_c, inv_c);
    sb_csr<<<NSB, 256, 0, stream>>>(packed_d, bbase_d, total_d, csr_d, offs_d, deg_d, inv_d);
    prep_misc<<<512, 256, 0, stream>>>(x, W1l, W1r, xp32, xp16, W1lp, W1rp);

    // L1: conv1 (x, eic)
    sage_spmm<false><<<NSB, 256, 0, stream>>>(
        xp32, xp16, nullptr, nullptr, nullptr,
        deg_c, inv_c, gbin_c, packed2_c, W1lp, W1rp, r_a, h16_a, stats + 0);
    // L2: conv4 (eic), BN1 folded
    sage_spmm<true><<<NSB, 256, 0, stream>>>(
        r_a, h16_a, stats + 0, g1, b1,
        deg_c, inv_c, gbin_c, packed2_c, W4l, W4r, r_b, h16_b, stats + 256);
    // L3: conv2 (eid), BN2 folded — small gather layer
    sage_layer8<true><<<2048, 256, 0, stream>>>(
        r_b, h16_b, stats + 256, g2, b2,
        offs_d, deg_d, csr_d, inv_d, W2l, W2r, r_a, h16_a, stats + 512);
    // L4: conv3 (eic), BN3 folded
    sage_spmm<true><<<NSB, 256, 0, stream>>>(
        r_a, h16_a, stats + 512, g3, b3,
        deg_c, inv_c, gbin_c, packed2_c, W3l, W3r, r_b, h16_b, stats + 768);
    // L5: conv3 (eic), BN4 folded
    sage_spmm<true><<<NSB, 256, 0, stream>>>(
        r_b, h16_b, stats + 768, g4, b4,
        deg_c, inv_c, gbin_c, packed2_c, W3l, W3r, r_a, h16_a, stats + 1024);
    apply_bn_out<<<(NN * 8 + 255) / 256, 256, 0, stream>>>(r_a, stats + 1024, g4, b4, out);
}

// Round 13
// 614.886 us; speedup vs baseline: 3.0774x; 3.0774x over previous
//
#include <hip/hip_runtime.h>
#include <hip/hip_fp16.h>

#define NN 100000
#define EC 6400000
#define ED 400000
#define BN_EPS 1e-5f
#define NSB ((NN + 255) >> 8)    // 391 buckets of 256 nodes
#define NCH 256                  // edge chunks per graph
#define CSR_CAP 19200            // LDS CSR build capacity (mean 16384 + slack)
#define CHUNK_OF(E) (((((E) + NCH - 1) / NCH) + 3) & ~3)   // 4-aligned chunk

// ---------------- fused preprocessing (R11 bodies, branched grids) ------------
// 18 dispatches -> 10: the ~150us unexplained residual matches ~8us/dispatch
// launch/drain gaps; eid work also now overlaps eic work within each kernel.

// grid = 2*NCH + 32: [0,NCH) eic hist, [NCH,2NCH) eid hist, rest = prep_misc
__global__ __launch_bounds__(1024)
void pre_hist_prep(const int* __restrict__ eic, const int* __restrict__ eid,
                   int* __restrict__ bhist_c, int* __restrict__ bhist_d,
                   const float* __restrict__ x, const float* __restrict__ W1l,
                   const float* __restrict__ W1r, float* __restrict__ xp,
                   __half* __restrict__ xp16,
                   float* __restrict__ W1lp, float* __restrict__ W1rp) {
    int blk = blockIdx.x;
    if (blk < 2 * NCH) {
        const int* ei = (blk < NCH) ? eic : eid;
        int E = (blk < NCH) ? EC : ED;
        int* bhist = (blk < NCH) ? bhist_c : bhist_d;
        int k = (blk < NCH) ? blk : blk - NCH;
        __shared__ int h[NSB];
        for (int i = threadIdx.x; i < NSB; i += 1024) h[i] = 0;
        __syncthreads();
        int chunk = CHUNK_OF(E);
        int beg = k * chunk, end = min(E, beg + chunk);
        for (int e = beg + threadIdx.x * 4; e < end; e += 1024 * 4) {
            int4 d4 = *(const int4*)&ei[E + e];
            atomicAdd(&h[d4.x >> 8], 1);
            atomicAdd(&h[d4.y >> 8], 1);
            atomicAdd(&h[d4.z >> 8], 1);
            atomicAdd(&h[d4.w >> 8], 1);
        }
        __syncthreads();
        for (int i = threadIdx.x; i < NSB; i += 1024) bhist[i * NCH + k] = h[i];
    } else {
        // prep: x -> f32 padded [NN,8] + fp16 copy; W1 -> padded 8x8
        int pb = blk - 2 * NCH;
        int t = pb * 1024 + threadIdx.x;
        if (t < 64) {
            int f = t >> 3, k = t & 7;
            W1lp[t] = (k < 5) ? W1l[f * 5 + k] : 0.f;
            W1rp[t] = (k < 5) ? W1r[f * 5 + k] : 0.f;
        }
        for (int idx = t; idx < NN * 8; idx += 32 * 1024) {
            int f = idx & 7, i = idx >> 3;
            float v = (f < 5) ? x[i * 5 + f] : 0.f;
            xp[idx] = v;
            xp16[idx] = __float2half(v);
        }
    }
}

// grid = 2*NSB: per-bucket exclusive scan over NCH chunk counts, both graphs
__global__ __launch_bounds__(256)
void row_scan2(int* __restrict__ bhist_c, int* __restrict__ total_c,
               int* __restrict__ bhist_d, int* __restrict__ total_d) {
    int blk = blockIdx.x;
    int* row = (blk < NSB) ? (bhist_c + blk * NCH)
                           : (bhist_d + (blk - NSB) * NCH);
    int* total = (blk < NSB) ? total_c : total_d;
    int bb = (blk < NSB) ? blk : blk - NSB;
    __shared__ int wsum[4];
    int lane = threadIdx.x & 63, w = threadIdx.x >> 6;
    int v = row[threadIdx.x];
    int x = v;
    #pragma unroll
    for (int sh = 1; sh < 64; sh <<= 1) { int y = __shfl_up(x, sh); if (lane >= sh) x += y; }
    if (lane == 63) wsum[w] = x;
    __syncthreads();
    int wb = 0;
    #pragma unroll
    for (int j = 0; j < 4; ++j) if (j < w) wb += wsum[j];
    row[threadIdx.x] = wb + x - v;
    if (threadIdx.x == 255) total[bb] = wb + x;
}

// one block: zero stats (replaces memset) + bucket bases for both graphs
__global__ void base2(const int* __restrict__ total_c, int* __restrict__ bbase_c,
                      const int* __restrict__ total_d, int* __restrict__ bbase_d,
                      float* __restrict__ stats) {
    for (int i = threadIdx.x; i < 5 * 256; i += 256) stats[i] = 0.f;
    __shared__ int wsum[4];
    __shared__ int carry;
    int lane = threadIdx.x & 63, w = threadIdx.x >> 6;
    for (int which = 0; which < 2; ++which) {
        const int* gt = which ? total_d : total_c;
        int* bb = which ? bbase_d : bbase_c;
        if (threadIdx.x == 0) carry = 0;
        __syncthreads();
        for (int s = 0; s < NSB; s += 256) {
            int idx = s + threadIdx.x;
            int v = (idx < NSB) ? gt[idx] : 0;
            int x = v;
            #pragma unroll
            for (int sh = 1; sh < 64; sh <<= 1) { int y = __shfl_up(x, sh); if (lane >= sh) x += y; }
            if (lane == 63) wsum[w] = x;
            __syncthreads();
            int wb = 0;
            #pragma unroll
            for (int j = 0; j < 4; ++j) if (j < w) wb += wsum[j];
            int all = wsum[0] + wsum[1] + wsum[2] + wsum[3];
            if (idx < NSB) bb[idx] = carry + wb + x - v;
            __syncthreads();
            if (threadIdx.x == 0) carry += all;
            __syncthreads();
        }
    }
}

// grid = 2*NCH: scatter into per-(chunk,bucket) regions, both graphs
__global__ __launch_bounds__(1024)
void scatter2(const int* __restrict__ eic, const int* __restrict__ eid,
              const int* __restrict__ bhist_c, const int* __restrict__ bbase_c,
              unsigned* __restrict__ packed_c,
              const int* __restrict__ bhist_d, const int* __restrict__ bbase_d,
              unsigned* __restrict__ packed_d) {
    int blk = blockIdx.x;
    const int* ei = (blk < NCH) ? eic : eid;
    int E = (blk < NCH) ? EC : ED;
    const int* bhist = (blk < NCH) ? bhist_c : bhist_d;
    const int* bbase = (blk < NCH) ? bbase_c : bbase_d;
    unsigned* packed = (blk < NCH) ? packed_c : packed_d;
    int k = (blk < NCH) ? blk : blk - NCH;
    __shared__ int cur[NSB];
    for (int b = threadIdx.x; b < NSB; b += 1024)
        cur[b] = bbase[b] + bhist[b * NCH + k];
    __syncthreads();
    int chunk = CHUNK_OF(E);
    int beg = k * chunk, end = min(E, beg + chunk);
    for (int e = beg + threadIdx.x * 4; e < end; e += 1024 * 4) {
        int4 s4 = *(const int4*)&ei[e];
        int4 d4 = *(const int4*)&ei[E + e];
        { int p = atomicAdd(&cur[d4.x >> 8], 1); packed[p] = (unsigned)s4.x | ((unsigned)(d4.x & 255) << 17); }
        { int p = atomicAdd(&cur[d4.y >> 8], 1); packed[p] = (unsigned)s4.y | ((unsigned)(d4.y & 255) << 17); }
        { int p = atomicAdd(&cur[d4.z >> 8], 1); packed[p] = (unsigned)s4.z | ((unsigned)(d4.z & 255) << 17); }
        { int p = atomicAdd(&cur[d4.w >> 8], 1); packed[p] = (unsigned)s4.w | ((unsigned)(d4.w & 255) << 17); }
    }
}

// grid = 2*NSB: exact per-node CSR via LDS, both graphs
__global__ __launch_bounds__(256)
void csr2(const unsigned* __restrict__ packed_c, const int* __restrict__ bbase_c,
          const int* __restrict__ total_c, int* __restrict__ csr_c,
          int* __restrict__ offs_c, int* __restrict__ deg_c, float* __restrict__ inv_c,
          const unsigned* __restrict__ packed_d, const int* __restrict__ bbase_d,
          const int* __restrict__ total_d, int* __restrict__ csr_d,
          int* __restrict__ offs_d, int* __restrict__ deg_d, float* __restrict__ inv_d) {
    int blk = blockIdx.x;
    const unsigned* packed = (blk < NSB) ? packed_c : packed_d;
    const int* bbase = (blk < NSB) ? bbase_c : bbase_d;
    const int* total = (blk < NSB) ? total_c : total_d;
    int* csr  = (blk < NSB) ? csr_c : csr_d;
    int* offs = (blk < NSB) ? offs_c : offs_d;
    int* deg  = (blk < NSB) ? deg_c : deg_d;
    float* inv = (blk < NSB) ? inv_c : inv_d;
    int b = (blk < NSB) ? blk : blk - NSB;

    __shared__ int h[256];
    __shared__ int loff[256];
    __shared__ int ws2[4];
    __shared__ int ebuf[CSR_CAP];
    int ebeg = bbase[b], ecnt = total[b];
    int node0 = b << 8;
    int nn = min(256, NN - node0);
    h[threadIdx.x] = 0;
    __syncthreads();
    for (int e = threadIdx.x; e < ecnt; e += 256)
        atomicAdd(&h[packed[ebeg + e] >> 17], 1);
    __syncthreads();
    {
        int lane = threadIdx.x & 63, w = threadIdx.x >> 6;
        int v = h[threadIdx.x], x = v;
        #pragma unroll
        for (int sh = 1; sh < 64; sh <<= 1) { int y = __shfl_up(x, sh); if (lane >= sh) x += y; }
        if (lane == 63) ws2[w] = x;
        __syncthreads();
        int wb = 0;
        #pragma unroll
        for (int j = 0; j < 4; ++j) if (j < w) wb += ws2[j];
        int excl = wb + x - v;
        loff[threadIdx.x] = excl;
        if (threadIdx.x < nn) {
            int node = node0 + threadIdx.x;
            offs[node] = ebeg + excl;
            deg[node]  = v;
            inv[node]  = 1.0f / (float)(v > 1 ? v : 1);
        }
    }
    __syncthreads();
    if (ecnt <= CSR_CAP) {
        for (int e = threadIdx.x; e < ecnt; e += 256) {
            unsigned u = packed[ebeg + e];
            int p = atomicAdd(&loff[u >> 17], 1);
            ebuf[p] = (int)(u & 0x1FFFF);
        }
        __syncthreads();
        for (int e = threadIdx.x; e < ecnt; e += 256) csr[ebeg + e] = ebuf[e];
    } else {
        for (int e = threadIdx.x; e < ecnt; e += 256) {
            unsigned u = packed[ebeg + e];
            int p = atomicAdd(&loff[u >> 17], 1);
            csr[ebeg + p] = (int)(u & 0x1FFFF);
        }
    }
}

// ---------------- fused SAGE layer v6 (R11, proven best: 83us/eic layer) -----
// fp16 gather rows (ONE dwordx4/edge), f32 self-term rows; deg=0 BN-shift fix.
template<bool APPLY_BN>
__global__ __launch_bounds__(256)
void sage_layer8(const float* __restrict__ hin,       // f32 rows (self-term)
                 const __half* __restrict__ hin16,    // fp16 rows (gather)
                 const float* __restrict__ stats_in,  // [k*16]=sum, [(8+k)*16]=sumsq
                 const float* __restrict__ gin, const float* __restrict__ bin,
                 const int* __restrict__ offs, const int* __restrict__ deg,
                 const int* __restrict__ csr, const float* __restrict__ inv,
                 const float* __restrict__ Wl, const float* __restrict__ Wr,
                 float* __restrict__ hout, __half* __restrict__ hout16,
                 float* __restrict__ stats_out) {
    __shared__ float bl[16];
    int tid = threadIdx.x;
    if (tid < 16) bl[tid] = 0.f;
    __syncthreads();
    int wave = tid >> 6, lane = tid & 63, g = lane >> 3, f = lane & 7;

    float sc[8], sh[8];
    #pragma unroll
    for (int k = 0; k < 8; ++k) { sc[k] = 1.f; sh[k] = 0.f; }
    if constexpr (APPLY_BN) {
        #pragma unroll
        for (int k = 0; k < 8; ++k) {
            float m = stats_in[k * 16] * (1.f / NN);
            float v = stats_in[(8 + k) * 16] * (1.f / NN) - m * m;
            float is = rsqrtf(v + BN_EPS);
            sc[k] = gin[k] * is;
            sh[k] = bin[k] - m * sc[k];
        }
    }
    float wl[8], wr[8];
    #pragma unroll
    for (int k = 0; k < 8; ++k) { wl[k] = Wl[f * 8 + k]; wr[k] = Wr[f * 8 + k]; }

    float acc_r = 0.f, acc_r2 = 0.f;
    const int stride = gridDim.x * 32;            // blocks * 4 waves * 8 nodes
    for (int i0 = (blockIdx.x * 4 + wave) * 8; i0 < NN; i0 += stride) {
        int i = i0 + g;
        int ic = min(i, NN - 1);
        bool ok = (i < NN);
        int d = ok ? deg[ic] : 0;
        int o = offs[ic];
        float a0 = 0, a1 = 0, a2 = 0, a3 = 0, a4 = 0, a5 = 0, a6 = 0, a7 = 0;
        for (int b = 0; b < d; b += 8) {          // divergent per group: exec-masked
            int e = b + f;
            int cv = csr[o + e];                  // <=7 over-read: csr tail-padded
            float m = (e < d) ? 1.f : 0.f;
            unsigned s = min((unsigned)cv & 0x1FFFFu, (unsigned)(NN - 1));
            uint4 rv = *(const uint4*)(hin16 + (size_t)s * 8);   // ONE 16B instr/edge
            float2 p0 = __half22float2(*(const __half2*)&rv.x);
            float2 p1 = __half22float2(*(const __half2*)&rv.y);
            float2 p2 = __half22float2(*(const __half2*)&rv.z);
            float2 p3 = __half22float2(*(const __half2*)&rv.w);
            a0 = fmaf(p0.x, m, a0); a1 = fmaf(p0.y, m, a1);
            a2 = fmaf(p1.x, m, a2); a3 = fmaf(p1.y, m, a3);
            a4 = fmaf(p2.x, m, a4); a5 = fmaf(p2.y, m, a5);
            a6 = fmaf(p3.x, m, a6); a7 = fmaf(p3.y, m, a7);
        }
        #pragma unroll
        for (int msk = 1; msk < 8; msk <<= 1) {   // group-wide sums, all lanes
            a0 += __shfl_xor(a0, msk); a1 += __shfl_xor(a1, msk);
            a2 += __shfl_xor(a2, msk); a3 += __shfl_xor(a3, msk);
            a4 += __shfl_xor(a4, msk); a5 += __shfl_xor(a5, msk);
            a6 += __shfl_xor(a6, msk); a7 += __shfl_xor(a7, msk);
        }
        float im = inv[ic];
        float dnz = (d > 0) ? 1.f : 0.f;          // BN shift only if node has neighbors
        const float4* hp = (const float4*)(hin + (size_t)ic * 8);   // exact f32 self row
        float4 h0 = hp[0];
        float4 h1 = hp[1];
        float hk[8] = { h0.x, h0.y, h0.z, h0.w, h1.x, h1.y, h1.z, h1.w };
        float ac[8] = { a0, a1, a2, a3, a4, a5, a6, a7 };
        float y = 0.f;
        #pragma unroll
        for (int k = 0; k < 8; ++k) {
            float mk = fmaf(sc[k], ac[k] * im, sh[k] * dnz);
            float hh = fmaf(sc[k], hk[k], sh[k]);
            y = fmaf(mk, wl[k], y);
            y = fmaf(hh, wr[k], y);
        }
        float n2 = y * y;
        n2 += __shfl_xor(n2, 1);
        n2 += __shfl_xor(n2, 2);
        n2 += __shfl_xor(n2, 4);
        float z = y / fmaxf(sqrtf(n2), 1e-12f);
        float r = fmaxf(z, 0.f);
        r = ok ? r : 0.f;
        if (ok) {
            hout[(size_t)i * 8 + f] = r;                   // f32 row (exact)
            hout16[(size_t)i * 8 + f] = __float2half(r);   // fp16 row (gather copy)
        }
        acc_r += r;
        acc_r2 += r * r;
    }
    atomicAdd(&bl[f], acc_r);
    atomicAdd(&bl[8 + f], acc_r2);
    __syncthreads();
    if (tid < 16) atomicAdd(&stats_out[tid * 16], bl[tid]);   // 1 cache line per feature
}

__global__ void apply_bn_out(const float* __restrict__ hin,
                             const float* __restrict__ stats,
                             const float* __restrict__ g, const float* __restrict__ b,
                             float* __restrict__ out) {
    int t = blockIdx.x * blockDim.x + threadIdx.x;
    if (t >= NN * 8) return;
    int f = t & 7;
    float m = stats[f * 16] * (1.0f / NN);
    float v = stats[(8 + f) * 16] * (1.0f / NN) - m * m;
    float sc = g[f] * rsqrtf(v + BN_EPS);
    float sh = b[f] - m * sc;
    out[t] = fmaf(hin[t], sc, sh);
}

// ---------------- launch ----------------

static inline char* bump(char*& p, size_t bytes) {
    char* r = p;
    p += (bytes + 255) & ~(size_t)255;
    return r;
}

extern "C" void kernel_launch(void* const* d_in, const int* in_sizes, int n_in,
                              void* d_out, int out_size, void* d_ws, size_t ws_size,
                              hipStream_t stream) {
    const float* x   = (const float*)d_in[0];
    const int* eic   = (const int*)d_in[1];
    const int* eid   = (const int*)d_in[2];
    const float* W1l = (const float*)d_in[3];
    const float* W1r = (const float*)d_in[4];
    const float* W2l = (const float*)d_in[5];
    const float* W2r = (const float*)d_in[6];
    const float* W3l = (const float*)d_in[7];
    const float* W3r = (const float*)d_in[8];
    const float* W4l = (const float*)d_in[9];
    const float* W4r = (const float*)d_in[10];
    const float* g1 = (const float*)d_in[11];
    const float* b1 = (const float*)d_in[12];
    const float* g2 = (const float*)d_in[13];
    const float* b2 = (const float*)d_in[14];
    const float* g3 = (const float*)d_in[15];
    const float* b3 = (const float*)d_in[16];
    const float* g4 = (const float*)d_in[17];
    const float* b4 = (const float*)d_in[18];
    float* out = (float*)d_out;

    char* p = (char*)d_ws;
    float* stats   = (float*)bump(p, 5 * 256 * 4);   // zeroed by base2 each call
    int*   bhist_c = (int*)  bump(p, (size_t)NSB * NCH * 4);
    int*   bhist_d = (int*)  bump(p, (size_t)NSB * NCH * 4);
    int*   total_c = (int*)  bump(p, NSB * 4);
    int*   bbase_c = (int*)  bump(p, NSB * 4);
    int*   total_d = (int*)  bump(p, NSB * 4);
    int*   bbase_d = (int*)  bump(p, NSB * 4);
    int*   offs_c  = (int*)  bump(p, NN * 4);
    int*   deg_c   = (int*)  bump(p, NN * 4);
    float* inv_c   = (float*)bump(p, NN * 4);
    int*   offs_d  = (int*)  bump(p, NN * 4);
    int*   deg_d   = (int*)  bump(p, NN * 4);
    float* inv_d   = (float*)bump(p, NN * 4);
    int*   csr_c   = (int*)  bump(p, ((size_t)EC + 64) * 4);   // +64 over-read pad
    int*   csr_d   = (int*)  bump(p, ((size_t)ED + 64) * 4);
    float* xp32    = (float*)bump(p, (size_t)NN * 8 * 4);
    __half* xp16   = (__half*)bump(p, (size_t)NN * 8 * 2);
    float* W1lp    = (float*)bump(p, 64 * 4);
    float* W1rp    = (float*)bump(p, 64 * 4);
    unsigned* packed_d = (unsigned*)bump(p, (size_t)ED * 4);
    // packed_c dead after csr2; overlay activation ping-pong (f32 + fp16)
    char* pc = p;
    unsigned* packed_c = (unsigned*)bump(p, (size_t)EC * 4);
    char* pr = pc;
    float*  r_a   = (float*) bump(pr, (size_t)NN * 8 * 4);
    float*  r_b   = (float*) bump(pr, (size_t)NN * 8 * 4);
    __half* h16_a = (__half*)bump(pr, (size_t)NN * 8 * 2);
    __half* h16_b = (__half*)bump(pr, (size_t)NN * 8 * 2);
    (void)ws_size; (void)in_sizes; (void)n_in; (void)out_size;

    // 10 dispatches total (was 18)
    pre_hist_prep<<<2 * NCH + 32, 1024, 0, stream>>>(
        eic, eid, bhist_c, bhist_d, x, W1l, W1r, xp32, xp16, W1lp, W1rp);
    row_scan2<<<2 * NSB, 256, 0, stream>>>(bhist_c, total_c, bhist_d, total_d);
    base2<<<1, 256, 0, stream>>>(total_c, bbase_c, total_d, bbase_d, stats);
    scatter2<<<2 * NCH, 1024, 0, stream>>>(
        eic, eid, bhist_c, bbase_c, packed_c, bhist_d, bbase_d, packed_d);
    csr2<<<2 * NSB, 256, 0, stream>>>(
        packed_c, bbase_c, total_c, csr_c, offs_c, deg_c, inv_c,
        packed_d, bbase_d, total_d, csr_d, offs_d, deg_d, inv_d);

    const int LB = 2048;   // 8192 waves x 8 nodes/wave per grid-iteration
    sage_layer8<false><<<LB, 256, 0, stream>>>(
        xp32, xp16, nullptr, nullptr, nullptr,
        offs_c, deg_c, csr_c, inv_c, W1lp, W1rp, r_a, h16_a, stats + 0);
    sage_layer8<true><<<LB, 256, 0, stream>>>(
        r_a, h16_a, stats + 0, g1, b1,
        offs_c, deg_c, csr_c, inv_c, W4l, W4r, r_b, h16_b, stats + 256);
    sage_layer8<true><<<LB, 256, 0, stream>>>(
        r_b, h16_b, stats + 256, g2, b2,
        offs_d, deg_d, csr_d, inv_d, W2l, W2r, r_a, h16_a, stats + 512);
    sage_layer8<true><<<LB, 256, 0, stream>>>(
        r_a, h16_a, stats + 512, g3, b3,
        offs_c, deg_c, csr_c, inv_c, W3l, W3r, r_b, h16_b, stats + 768);
    sage_layer8<true><<<LB, 256, 0, stream>>>(
        r_b, h16_b, stats + 768, g4, b4,
        offs_c, deg_c, csr_c, inv_c, W3l, W3r, r_a, h16_a, stats + 1024);
    apply_bn_out<<<(NN * 8 + 255) / 256, 256, 0, stream>>>(r_a, stats + 1024, g4, b4, out);
}